// Round 3
// baseline (978.419 us; speedup 1.0000x reference)
//
#include <hip/hip_runtime.h>
#include <hip/hip_bf16.h>
#include <stdint.h>

#define T_ 2048
#define H_ 1024
#define I_ 2048
#define E_ 8
#define NE_ 9            // 8 routed + 1 shared (virtual expert)
#define BM 128
#define BK 32
#define BN 64
#define BNP 66           // padded n-row stride (halves): bank = k + n/2 -> conflict-free u16 gather

typedef __attribute__((ext_vector_type(8))) short bf16x8;
typedef __attribute__((ext_vector_type(4))) float f32x4;

__device__ __forceinline__ unsigned short f2bf(float f) {
  unsigned int u; __builtin_memcpy(&u, &f, 4);
  u = (u + 0x7fffu + ((u >> 16) & 1u)) >> 16;
  return (unsigned short)u;
}
__device__ __forceinline__ void cvt2(float a, float b, unsigned short* dst) {
  __hip_bfloat162 h = __float22bfloat162_rn(float2{a, b});
  __builtin_memcpy(dst, &h, 4);
}

// ---------------- router: 1 wave per token, all fp32 ----------------
__global__ __launch_bounds__(256) void k_router(
    const float* __restrict__ x, const float* __restrict__ rw,
    float* zacc, float* pacc, int* cnt, int* topi, float* topw) {
  __shared__ float lds_rw[H_ * E_];  // 32 KB
  int tid = threadIdx.x;
#pragma unroll
  for (int i = 0; i < 8; i++)
    ((float4*)lds_rw)[i * 256 + tid] = ((const float4*)rw)[i * 256 + tid];
  __syncthreads();
  int wid = tid >> 6, lane = tid & 63;
  int t = blockIdx.x * 4 + wid;
  const float4* xv = (const float4*)(x + (size_t)t * H_ + lane * 16);
  float xr[16];
#pragma unroll
  for (int q = 0; q < 4; q++) {
    float4 v = xv[q];
    xr[q * 4] = v.x; xr[q * 4 + 1] = v.y; xr[q * 4 + 2] = v.z; xr[q * 4 + 3] = v.w;
  }
  float acc[E_];
#pragma unroll
  for (int e = 0; e < E_; e++) acc[e] = 0.f;
#pragma unroll
  for (int j = 0; j < 16; j++) {
    float xf = xr[j];
    const float* wrow = &lds_rw[(lane * 16 + j) * E_];
#pragma unroll
    for (int e = 0; e < E_; e++) acc[e] += xf * wrow[e];
  }
#pragma unroll
  for (int off = 32; off >= 1; off >>= 1) {
#pragma unroll
    for (int e = 0; e < E_; e++) acc[e] += __shfl_xor(acc[e], off, 64);
  }
  if (lane == 0) {
    float m = acc[0];
#pragma unroll
    for (int e = 1; e < E_; e++) m = fmaxf(m, acc[e]);
    float p[E_], s = 0.f;
#pragma unroll
    for (int e = 0; e < E_; e++) { p[e] = expf(acc[e] - m); s += p[e]; }
    float inv = 1.f / s;
#pragma unroll
    for (int e = 0; e < E_; e++) p[e] *= inv;
    float lse = m + logf(s);
    atomicAdd(zacc, lse * lse);
#pragma unroll
    for (int e = 0; e < E_; e++) atomicAdd(&pacc[e], p[e]);
    int i0 = 0;
#pragma unroll
    for (int e = 1; e < E_; e++) if (p[e] > p[i0]) i0 = e;
    int i1 = (i0 == 0) ? 1 : 0;
#pragma unroll
    for (int e = 0; e < E_; e++) if (e != i0 && e != i1 && p[e] > p[i1]) i1 = e;
    float w0 = p[i0], w1 = p[i1], wsum = w0 + w1;
    w0 /= wsum; w1 /= wsum;
    topi[t * 2] = i0; topi[t * 2 + 1] = i1;
    topw[t * 2] = w0; topw[t * 2 + 1] = w1;
    atomicAdd(&cnt[i0], 1); atomicAdd(&cnt[i1], 1);
  }
}

// ---------------- scan: offsets + aux loss ----------------
__global__ void k_scan(const float* zacc, const float* pacc, int* cnt, int* offs,
                       float* out_aux) {
  if (threadIdx.x == 0 && blockIdx.x == 0) {
    cnt[E_] = T_;
    int o = 0;
    for (int e = 0; e < NE_; e++) { offs[e] = o; o += cnt[e]; }
    offs[NE_] = o;
    float lb = 0.f;
    for (int e = 0; e < E_; e++)
      lb += ((float)cnt[e] / 4096.f) * (pacc[e] / 2048.f);
    out_aux[0] = 0.01f * 8.f * lb + 0.001f * (zacc[0] / 2048.f);
  }
}

// ---------------- fill: compact expert token lists ----------------
__global__ __launch_bounds__(256) void k_fill(
    const int* __restrict__ topi, const float* __restrict__ topw,
    const int* __restrict__ offs, int* cur, int* tok, float* wgt) {
  int t = blockIdx.x * 256 + threadIdx.x;
#pragma unroll
  for (int k = 0; k < 2; k++) {
    int e = topi[t * 2 + k];
    int pos = atomicAdd(&cur[e], 1);
    tok[offs[e] + pos] = t;
    wgt[offs[e] + pos] = topw[t * 2 + k];
  }
  tok[4096 + t] = t;
  wgt[4096 + t] = 1.f;
}

// ---------------- GEMM1: h = silu(x*Wg) * (x*Wu) ----------------
// double-buffered LDS, 1 barrier/iter; loads(k+1) overlap MFMA(k).
__global__ __launch_bounds__(256) void k_gemm1(
    const float* __restrict__ x,
    const float* __restrict__ eg, const float* __restrict__ eu,
    const float* __restrict__ sg, const float* __restrict__ su,
    const int* __restrict__ cnt, const int* __restrict__ offs,
    const int* __restrict__ tok, unsigned short* __restrict__ hbuf) {
  int mt = blockIdx.x, nt = blockIdx.y, e = blockIdx.z;
  int cnt_e = cnt[e];
  if (mt * BM >= cnt_e) return;
  int offs_e = offs[e];
  const float* Bg = (e < E_) ? eg + (size_t)e * H_ * I_ : sg;
  const float* Bu = (e < E_) ? eu + (size_t)e * H_ * I_ : su;
  int n0 = nt * BN;

  __shared__ __align__(16) unsigned short As[2][4][BM][8];  // [buf][kg][m][8h] -> b128 frag reads
  __shared__ unsigned short BgS[2][BK][BNP];                // [buf][k][n] stride 66
  __shared__ unsigned short BuS[2][BK][BNP];

  int tid = threadIdx.x;
  // A staging: thread -> (row m, 16-float half)
  int am = tid >> 1, ah = tid & 1;
  int atok = tok[offs_e + min(mt * BM + am, cnt_e - 1)];
  const float* aptr = x + (size_t)atok * H_ + ah * 16;
  // B staging: thread -> (k rows bkq & bkq+16, float4 col group)
  int bkq = tid >> 4, bf4 = tid & 15;
  const float* bgp = Bg + (size_t)bkq * I_ + n0 + bf4 * 4;
  const float* bup = Bu + (size_t)bkq * I_ + n0 + bf4 * 4;

  int lane = tid & 63, wid = tid >> 6;
  int quad = lane >> 4, l15 = lane & 15;
  int wm = wid >> 1, wn = wid & 1;

  f32x4 zero = {0.f, 0.f, 0.f, 0.f};
  f32x4 accg[4][2], accu[4][2];
#pragma unroll
  for (int mi = 0; mi < 4; mi++)
#pragma unroll
    for (int ni = 0; ni < 2; ni++) { accg[mi][ni] = zero; accu[mi][ni] = zero; }

  float4 av[4], bgv[2], buv[2];
  // prologue: load tile 0
#pragma unroll
  for (int q = 0; q < 4; q++) av[q] = ((const float4*)aptr)[q];
  bgv[0] = *(const float4*)bgp;              bgv[1] = *(const float4*)(bgp + (size_t)16 * I_);
  buv[0] = *(const float4*)bup;              buv[1] = *(const float4*)(bup + (size_t)16 * I_);
  // stage tile 0 -> buf 0
  {
#pragma unroll
    for (int g = 0; g < 2; g++) {
      unsigned short t8[8];
      cvt2(av[2*g].x, av[2*g].y, t8); cvt2(av[2*g].z, av[2*g].w, t8+2);
      cvt2(av[2*g+1].x, av[2*g+1].y, t8+4); cvt2(av[2*g+1].z, av[2*g+1].w, t8+6);
      *(bf16x8*)&As[0][ah*2+g][am][0] = *(bf16x8*)t8;
    }
#pragma unroll
    for (int c = 0; c < 2; c++) {
      unsigned short t4[4];
      cvt2(bgv[c].x, bgv[c].y, t4); cvt2(bgv[c].z, bgv[c].w, t4+2);
      *(unsigned int*)&BgS[0][bkq+16*c][bf4*4] = *(unsigned int*)t4;
      *(unsigned int*)&BgS[0][bkq+16*c][bf4*4+2] = *(unsigned int*)(t4+2);
      cvt2(buv[c].x, buv[c].y, t4); cvt2(buv[c].z, buv[c].w, t4+2);
      *(unsigned int*)&BuS[0][bkq+16*c][bf4*4] = *(unsigned int*)t4;
      *(unsigned int*)&BuS[0][bkq+16*c][bf4*4+2] = *(unsigned int*)(t4+2);
    }
  }
  __syncthreads();

  for (int kt = 0; kt < H_ / BK; kt++) {
    int kn = (kt + 1 < H_ / BK) ? (kt + 1) * BK : 0;  // clamp: last iter reloads tile 0 (discarded)
    // issue loads for next tile (consumed after MFMA -> latency hidden)
#pragma unroll
    for (int q = 0; q < 4; q++) av[q] = ((const float4*)(aptr + kn))[q];
    bgv[0] = *(const float4*)(bgp + (size_t)kn * I_);
    bgv[1] = *(const float4*)(bgp + (size_t)(kn + 16) * I_);
    buv[0] = *(const float4*)(bup + (size_t)kn * I_);
    buv[1] = *(const float4*)(bup + (size_t)(kn + 16) * I_);

    int cb = kt & 1;
    bf16x8 af[4];
#pragma unroll
    for (int mi = 0; mi < 4; mi++)
      af[mi] = *(const bf16x8*)&As[cb][quad][wm*64 + mi*16 + l15][0];
#pragma unroll
    for (int ni = 0; ni < 2; ni++) {
      int n = wn*32 + ni*16 + l15;
      bf16x8 bg, bu;
#pragma unroll
      for (int j = 0; j < 8; j++) {
        bg[j] = (short)BgS[cb][quad*8 + j][n];
        bu[j] = (short)BuS[cb][quad*8 + j][n];
      }
#pragma unroll
      for (int mi = 0; mi < 4; mi++) {
        accg[mi][ni] = __builtin_amdgcn_mfma_f32_16x16x32_bf16(af[mi], bg, accg[mi][ni], 0, 0, 0);
        accu[mi][ni] = __builtin_amdgcn_mfma_f32_16x16x32_bf16(af[mi], bu, accu[mi][ni], 0, 0, 0);
      }
    }
    // stage next tile into other buffer (vmcnt wait lands here, after MFMA)
    int nb = cb ^ 1;
#pragma unroll
    for (int g = 0; g < 2; g++) {
      unsigned short t8[8];
      cvt2(av[2*g].x, av[2*g].y, t8); cvt2(av[2*g].z, av[2*g].w, t8+2);
      cvt2(av[2*g+1].x, av[2*g+1].y, t8+4); cvt2(av[2*g+1].z, av[2*g+1].w, t8+6);
      *(bf16x8*)&As[nb][ah*2+g][am][0] = *(bf16x8*)t8;
    }
#pragma unroll
    for (int c = 0; c < 2; c++) {
      unsigned short t4[4];
      cvt2(bgv[c].x, bgv[c].y, t4); cvt2(bgv[c].z, bgv[c].w, t4+2);
      *(unsigned int*)&BgS[nb][bkq+16*c][bf4*4] = *(unsigned int*)t4;
      *(unsigned int*)&BgS[nb][bkq+16*c][bf4*4+2] = *(unsigned int*)(t4+2);
      cvt2(buv[c].x, buv[c].y, t4); cvt2(buv[c].z, buv[c].w, t4+2);
      *(unsigned int*)&BuS[nb][bkq+16*c][bf4*4] = *(unsigned int*)t4;
      *(unsigned int*)&BuS[nb][bkq+16*c][bf4*4+2] = *(unsigned int*)(t4+2);
    }
    __syncthreads();
  }

  // epilogue: h = silu(g)*u -> bf16 hbuf
#pragma unroll
  for (int mi = 0; mi < 4; mi++)
#pragma unroll
    for (int ni = 0; ni < 2; ni++) {
      int col = n0 + wn*32 + ni*16 + l15;
#pragma unroll
      for (int r = 0; r < 4; r++) {
        int row = mt * BM + wm*64 + mi*16 + quad*4 + r;
        if (row < cnt_e) {
          float g = accg[mi][ni][r], u = accu[mi][ni][r];
          float sv = g / (1.f + __expf(-g));
          hbuf[(size_t)(offs_e + row) * I_ + col] = f2bf(sv * u);
        }
      }
    }
}

// ---------------- GEMM2: out += w * (h * Wd), fp32 atomic scatter ----------------
__global__ __launch_bounds__(256) void k_gemm2(
    const unsigned short* __restrict__ hbuf,
    const float* __restrict__ ed, const float* __restrict__ sd,
    const int* __restrict__ cnt, const int* __restrict__ offs,
    const int* __restrict__ tok, const float* __restrict__ wgt,
    float* __restrict__ out) {
  int mt = blockIdx.x, nt = blockIdx.y, e = blockIdx.z;
  int cnt_e = cnt[e];
  if (mt * BM >= cnt_e) return;
  int offs_e = offs[e];
  const float* Bd = (e < E_) ? ed + (size_t)e * I_ * H_ : sd;
  int n0 = nt * BN;

  __shared__ __align__(16) unsigned short As[2][4][BM][8];
  __shared__ unsigned short BdS[2][BK][BNP];

  int tid = threadIdx.x;
  int am = tid >> 1, ah = tid & 1;
  const unsigned short* aptr =
      hbuf + (size_t)(offs_e + min(mt * BM + am, cnt_e - 1)) * I_ + ah * 16;
  int bkq = tid >> 4, bf4 = tid & 15;
  const float* bdp = Bd + (size_t)bkq * H_ + n0 + bf4 * 4;

  int lane = tid & 63, wid = tid >> 6;
  int quad = lane >> 4, l15 = lane & 15;
  int wm = wid >> 1, wn = wid & 1;

  f32x4 zero = {0.f, 0.f, 0.f, 0.f};
  f32x4 acc[4][2];
#pragma unroll
  for (int mi = 0; mi < 4; mi++)
#pragma unroll
    for (int ni = 0; ni < 2; ni++) acc[mi][ni] = zero;

  bf16x8 av8[2];
  float4 bdv[2];
  av8[0] = ((const bf16x8*)aptr)[0];
  av8[1] = ((const bf16x8*)aptr)[1];
  bdv[0] = *(const float4*)bdp;
  bdv[1] = *(const float4*)(bdp + (size_t)16 * H_);
  {
#pragma unroll
    for (int g = 0; g < 2; g++) *(bf16x8*)&As[0][ah*2+g][am][0] = av8[g];
#pragma unroll
    for (int c = 0; c < 2; c++) {
      unsigned short t4[4];
      cvt2(bdv[c].x, bdv[c].y, t4); cvt2(bdv[c].z, bdv[c].w, t4+2);
      *(unsigned int*)&BdS[0][bkq+16*c][bf4*4] = *(unsigned int*)t4;
      *(unsigned int*)&BdS[0][bkq+16*c][bf4*4+2] = *(unsigned int*)(t4+2);
    }
  }
  __syncthreads();

  for (int kt = 0; kt < I_ / BK; kt++) {
    int kn = (kt + 1 < I_ / BK) ? (kt + 1) * BK : 0;
    av8[0] = ((const bf16x8*)(aptr + kn))[0];
    av8[1] = ((const bf16x8*)(aptr + kn))[1];
    bdv[0] = *(const float4*)(bdp + (size_t)kn * H_);
    bdv[1] = *(const float4*)(bdp + (size_t)(kn + 16) * H_);

    int cb = kt & 1;
    bf16x8 af[4];
#pragma unroll
    for (int mi = 0; mi < 4; mi++)
      af[mi] = *(const bf16x8*)&As[cb][quad][wm*64 + mi*16 + l15][0];
#pragma unroll
    for (int ni = 0; ni < 2; ni++) {
      int n = wn*32 + ni*16 + l15;
      bf16x8 bd;
#pragma unroll
      for (int j = 0; j < 8; j++) bd[j] = (short)BdS[cb][quad*8 + j][n];
#pragma unroll
      for (int mi = 0; mi < 4; mi++)
        acc[mi][ni] = __builtin_amdgcn_mfma_f32_16x16x32_bf16(af[mi], bd, acc[mi][ni], 0, 0, 0);
    }
    int nb = cb ^ 1;
#pragma unroll
    for (int g = 0; g < 2; g++) *(bf16x8*)&As[nb][ah*2+g][am][0] = av8[g];
#pragma unroll
    for (int c = 0; c < 2; c++) {
      unsigned short t4[4];
      cvt2(bdv[c].x, bdv[c].y, t4); cvt2(bdv[c].z, bdv[c].w, t4+2);
      *(unsigned int*)&BdS[nb][bkq+16*c][bf4*4] = *(unsigned int*)t4;
      *(unsigned int*)&BdS[nb][bkq+16*c][bf4*4+2] = *(unsigned int*)(t4+2);
    }
    __syncthreads();
  }

#pragma unroll
  for (int mi = 0; mi < 4; mi++)
#pragma unroll
    for (int r = 0; r < 4; r++) {
      int row = mt * BM + wm*64 + mi*16 + quad*4 + r;
      if (row < cnt_e) {
        int tt = tok[offs_e + row];
        float w = wgt[offs_e + row];
#pragma unroll
        for (int ni = 0; ni < 2; ni++) {
          int col = n0 + wn*32 + ni*16 + l15;
          atomicAdd(&out[(size_t)tt * H_ + col], w * acc[mi][ni][r]);
        }
      }
    }
}

extern "C" void kernel_launch(void* const* d_in, const int* in_sizes, int n_in,
                              void* d_out, int out_size, void* d_ws, size_t ws_size,
                              hipStream_t stream) {
  const float* x  = (const float*)d_in[0];
  const float* rw = (const float*)d_in[1];
  const float* eg = (const float*)d_in[2];
  const float* eu = (const float*)d_in[3];
  const float* ed = (const float*)d_in[4];
  const float* sg = (const float*)d_in[5];
  const float* su = (const float*)d_in[6];
  const float* sd = (const float*)d_in[7];
  float* out = (float*)d_out;
  char* ws = (char*)d_ws;

  float* zacc = (float*)(ws + 0);
  float* pacc = (float*)(ws + 16);
  int*   cnt  = (int*)(ws + 64);
  int*   offs = (int*)(ws + 128);
  int*   cur  = (int*)(ws + 192);
  int*   topi = (int*)(ws + 512);
  float* topw = (float*)(ws + 512 + 16384);
  int*   tok  = (int*)(ws + 512 + 32768);
  float* wgt  = (float*)(ws + 512 + 32768 + 24576);
  unsigned short* hbuf = (unsigned short*)(ws + (1 << 20));  // 6144 x 2048 bf16 = 24 MB

  hipMemsetAsync(ws, 0, 512, stream);
  hipMemsetAsync(out, 0, (size_t)T_ * H_ * 4, stream);
  k_router<<<512, 256, 0, stream>>>(x, rw, zacc, pacc, cnt, topi, topw);
  k_scan<<<1, 64, 0, stream>>>(zacc, pacc, cnt, offs, out + (size_t)T_ * H_);
  k_fill<<<8, 256, 0, stream>>>(topi, topw, offs, cur, tok, wgt);
  dim3 g1(16, I_ / BN, NE_);
  k_gemm1<<<g1, 256, 0, stream>>>(x, eg, eu, sg, su, cnt, offs, tok, hbuf);
  dim3 g2(16, H_ / BN, NE_);
  k_gemm2<<<g2, 256, 0, stream>>>(hbuf, ed, sd, cnt, offs, tok, wgt, out);
}

// Round 4
// 779.040 us; speedup vs baseline: 1.2559x; 1.2559x over previous
//
#include <hip/hip_runtime.h>
#include <hip/hip_bf16.h>
#include <stdint.h>

#define T_ 2048
#define H_ 1024
#define I_ 2048
#define E_ 8
#define NE_ 9            // 8 routed + 1 shared (virtual expert)

typedef __attribute__((ext_vector_type(8))) short bf16x8;
typedef __attribute__((ext_vector_type(4))) float f32x4;

__device__ __forceinline__ unsigned short f2bf(float f) {
  unsigned int u; __builtin_memcpy(&u, &f, 4);
  u = (u + 0x7fffu + ((u >> 16) & 1u)) >> 16;
  return (unsigned short)u;
}
__device__ __forceinline__ void cvt2(float a, float b, unsigned short* dst) {
  __hip_bfloat162 h = __float22bfloat162_rn(float2{a, b});
  __builtin_memcpy(dst, &h, 4);
}
// async global->LDS DMA, 16B per lane; LDS dest = wave-uniform base + lane*16
__device__ __forceinline__ void gll16(const void* g, void* l) {
  __builtin_amdgcn_global_load_lds((const __attribute__((address_space(1))) void*)g,
                                   (__attribute__((address_space(3))) void*)l, 16, 0, 0);
}

// ---------------- pack weights: fp32 [K][N] -> bf16 blocked [nt64][kt32][q][nn][8] ----------------
// grid (64, 32, 27): z = grp*9+e; grp 0=gate,1=up,2=down
__global__ __launch_bounds__(256) void k_pack(
    const float* __restrict__ eg, const float* __restrict__ eu, const float* __restrict__ ed,
    const float* __restrict__ sg, const float* __restrict__ su, const float* __restrict__ sd,
    unsigned short* __restrict__ wgp, unsigned short* __restrict__ wup,
    unsigned short* __restrict__ wdp) {
  int kt = blockIdx.x, nt = blockIdx.y, z = blockIdx.z;
  int grp = z / NE_, e = z % NE_;
  int K = (grp == 2) ? I_ : H_;
  int N = (grp == 2) ? H_ : I_;
  if (kt * 32 >= K || nt * 64 >= N) return;
  const float* src; unsigned short* dst;
  if (grp == 0)      { src = (e < E_) ? eg + (size_t)e * H_ * I_ : sg; dst = wgp + (size_t)e * H_ * I_; }
  else if (grp == 1) { src = (e < E_) ? eu + (size_t)e * H_ * I_ : su; dst = wup + (size_t)e * H_ * I_; }
  else               { src = (e < E_) ? ed + (size_t)e * I_ * H_ : sd; dst = wdp + (size_t)e * I_ * H_; }
  int t = threadIdx.x;
  int q = t >> 6, nn = t & 63;
  int k0 = kt * 32 + q * 8, n = nt * 64 + nn;
  unsigned short o[8];
#pragma unroll
  for (int j = 0; j < 8; j += 2) {
    float a = src[(size_t)(k0 + j) * N + n];
    float b = src[(size_t)(k0 + j + 1) * N + n];
    cvt2(a, b, &o[j]);
  }
  size_t tile = ((size_t)nt * (K / 32) + kt) * 2048;
  *(bf16x8*)&dst[tile + q * 512 + nn * 8] = *(bf16x8*)o;
}

// ---------------- router: 1 wave per token, all fp32 ----------------
__global__ __launch_bounds__(256) void k_router(
    const float* __restrict__ x, const float* __restrict__ rw,
    float* zacc, float* pacc, int* cnt, int* topi, float* topw) {
  __shared__ float lds_rw[H_ * E_];
  int tid = threadIdx.x;
#pragma unroll
  for (int i = 0; i < 8; i++)
    ((float4*)lds_rw)[i * 256 + tid] = ((const float4*)rw)[i * 256 + tid];
  __syncthreads();
  int wid = tid >> 6, lane = tid & 63;
  int t = blockIdx.x * 4 + wid;
  const float4* xv = (const float4*)(x + (size_t)t * H_ + lane * 16);
  float xr[16];
#pragma unroll
  for (int q = 0; q < 4; q++) {
    float4 v = xv[q];
    xr[q * 4] = v.x; xr[q * 4 + 1] = v.y; xr[q * 4 + 2] = v.z; xr[q * 4 + 3] = v.w;
  }
  float acc[E_];
#pragma unroll
  for (int e = 0; e < E_; e++) acc[e] = 0.f;
#pragma unroll
  for (int j = 0; j < 16; j++) {
    float xf = xr[j];
    const float* wrow = &lds_rw[(lane * 16 + j) * E_];
#pragma unroll
    for (int e = 0; e < E_; e++) acc[e] += xf * wrow[e];
  }
#pragma unroll
  for (int off = 32; off >= 1; off >>= 1) {
#pragma unroll
    for (int e = 0; e < E_; e++) acc[e] += __shfl_xor(acc[e], off, 64);
  }
  if (lane == 0) {
    float m = acc[0];
#pragma unroll
    for (int e = 1; e < E_; e++) m = fmaxf(m, acc[e]);
    float p[E_], s = 0.f;
#pragma unroll
    for (int e = 0; e < E_; e++) { p[e] = expf(acc[e] - m); s += p[e]; }
    float inv = 1.f / s;
#pragma unroll
    for (int e = 0; e < E_; e++) p[e] *= inv;
    float lse = m + logf(s);
    atomicAdd(zacc, lse * lse);
#pragma unroll
    for (int e = 0; e < E_; e++) atomicAdd(&pacc[e], p[e]);
    int i0 = 0;
#pragma unroll
    for (int e = 1; e < E_; e++) if (p[e] > p[i0]) i0 = e;
    int i1 = (i0 == 0) ? 1 : 0;
#pragma unroll
    for (int e = 0; e < E_; e++) if (e != i0 && e != i1 && p[e] > p[i1]) i1 = e;
    float w0 = p[i0], w1 = p[i1], wsum = w0 + w1;
    w0 /= wsum; w1 /= wsum;
    topi[t * 2] = i0; topi[t * 2 + 1] = i1;
    topw[t * 2] = w0; topw[t * 2 + 1] = w1;
    atomicAdd(&cnt[i0], 1); atomicAdd(&cnt[i1], 1);
  }
}

// ---------------- scan: 128-padded offsets + aux loss ----------------
__global__ void k_scan(const float* zacc, const float* pacc, int* cnt, int* poffs,
                       float* out_aux) {
  if (threadIdx.x == 0 && blockIdx.x == 0) {
    cnt[E_] = T_;
    int po = 0;
    for (int e = 0; e < NE_; e++) { poffs[e] = po; po += ((cnt[e] + 127) >> 7) << 7; }
    poffs[NE_] = po;
    float lb = 0.f;
    for (int e = 0; e < E_; e++)
      lb += ((float)cnt[e] / 4096.f) * (pacc[e] / 2048.f);
    out_aux[0] = 0.01f * 8.f * lb + 0.001f * (zacc[0] / 2048.f);
  }
}

// ---------------- fill: compact expert token lists (into padded regions) ----------------
__global__ __launch_bounds__(256) void k_fill(
    const int* __restrict__ topi, const float* __restrict__ topw,
    const int* __restrict__ poffs, int* cur, int* tok, float* wgt) {
  int t = blockIdx.x * 256 + threadIdx.x;
#pragma unroll
  for (int k = 0; k < 2; k++) {
    int e = topi[t * 2 + k];
    int pos = atomicAdd(&cur[e], 1);
    tok[poffs[e] + pos] = t;
    wgt[poffs[e] + pos] = topw[t * 2 + k];
  }
  int p8 = poffs[E_];
  tok[p8 + t] = t;
  wgt[p8 + t] = 1.f;
}

// ---------------- packA: gather x rows -> bf16 blocked A [rt][kt][q][m][8] ----------------
// grid (8, 16, 9)
__global__ __launch_bounds__(256) void k_packA(
    const float* __restrict__ x, const int* __restrict__ cnt,
    const int* __restrict__ poffs, const int* __restrict__ tok,
    unsigned short* __restrict__ apack) {
  int kc = blockIdx.x, mt = blockIdx.y, e = blockIdx.z;
  int cnt_e = cnt[e];
  if (mt * 128 >= cnt_e) return;
  int po = poffs[e];
  int rt = (po >> 7) + mt;
  int t = threadIdx.x;
  int m = t & 127, qh = t >> 7;
  int atok = tok[po + min(mt * 128 + m, cnt_e - 1)];
  const float* arow = x + (size_t)atok * H_;
  size_t abase = (size_t)rt * 32 * 4096;
#pragma unroll
  for (int ki = 0; ki < 4; ki++) {
    int kt = kc * 4 + ki;
#pragma unroll
    for (int qo = 0; qo < 2; qo++) {
      int q = qh + qo * 2;
      const float* s = arow + kt * 32 + q * 8;
      float4 v0 = *(const float4*)s, v1 = *(const float4*)(s + 4);
      unsigned short t8[8];
      cvt2(v0.x, v0.y, t8); cvt2(v0.z, v0.w, t8 + 2);
      cvt2(v1.x, v1.y, t8 + 4); cvt2(v1.z, v1.w, t8 + 6);
      *(bf16x8*)&apack[abase + (size_t)kt * 4096 + q * 1024 + m * 8] = *(bf16x8*)t8;
    }
  }
}

// ---------------- GEMM1: h = silu(x*Wg)*(x*Wu); pure-DMA m97-style ----------------
// BM=128, BN=64 (gate+up), BK=32. grid (16, 32, 9).
__global__ __launch_bounds__(256) void k_gemm1(
    const unsigned short* __restrict__ apack,
    const unsigned short* __restrict__ wgp, const unsigned short* __restrict__ wup,
    const int* __restrict__ cnt, const int* __restrict__ poffs,
    unsigned short* __restrict__ hbuf) {
  int mt = blockIdx.x, nt = blockIdx.y, e = blockIdx.z;
  int cnt_e = cnt[e];
  if (mt * 128 >= cnt_e) return;
  int po = poffs[e];
  int rt = (po >> 7) + mt;

  __shared__ __align__(16) unsigned short As[4096];   // [q][m][8]
  __shared__ __align__(16) unsigned short BgS[2048];  // [q][nn][8]
  __shared__ __align__(16) unsigned short BuS[2048];

  int tid = threadIdx.x;
  int lane = tid & 63, w = tid >> 6;
  int quad = lane >> 4, l15 = lane & 15;
  int wm = w >> 1, wn = w & 1;

  const unsigned short* abase = apack + (size_t)rt * 32 * 4096;
  const unsigned short* bgb = wgp + (size_t)e * H_ * I_ + (size_t)nt * 32 * 2048;
  const unsigned short* bub = wup + (size_t)e * H_ * I_ + (size_t)nt * 32 * 2048;

  f32x4 zero = {0.f, 0.f, 0.f, 0.f};
  f32x4 accg[4][2], accu[4][2];
#pragma unroll
  for (int mi = 0; mi < 4; mi++)
#pragma unroll
    for (int ni = 0; ni < 2; ni++) { accg[mi][ni] = zero; accu[mi][ni] = zero; }

  for (int kt = 0; kt < 32; kt++) {
    __syncthreads();
    const unsigned short* asrc = abase + (size_t)kt * 4096 + w * 1024 + lane * 8;
    gll16(asrc, &As[w * 1024]);
    gll16(asrc + 512, &As[w * 1024 + 512]);
    gll16(bgb + (size_t)kt * 2048 + w * 512 + lane * 8, &BgS[w * 512]);
    gll16(bub + (size_t)kt * 2048 + w * 512 + lane * 8, &BuS[w * 512]);
    __syncthreads();
    bf16x8 af[4];
#pragma unroll
    for (int mi = 0; mi < 4; mi++)
      af[mi] = *(const bf16x8*)&As[quad * 1024 + (wm * 64 + mi * 16 + l15) * 8];
#pragma unroll
    for (int ni = 0; ni < 2; ni++) {
      bf16x8 bg = *(const bf16x8*)&BgS[quad * 512 + (wn * 32 + ni * 16 + l15) * 8];
      bf16x8 bu = *(const bf16x8*)&BuS[quad * 512 + (wn * 32 + ni * 16 + l15) * 8];
#pragma unroll
      for (int mi = 0; mi < 4; mi++) {
        accg[mi][ni] = __builtin_amdgcn_mfma_f32_16x16x32_bf16(af[mi], bg, accg[mi][ni], 0, 0, 0);
        accu[mi][ni] = __builtin_amdgcn_mfma_f32_16x16x32_bf16(af[mi], bu, accu[mi][ni], 0, 0, 0);
      }
    }
  }
  // epilogue: silu(g)*u -> hbuf in gemm2's packed-A layout [rt][kt2][q2][m][8]
  size_t hbase = (size_t)rt * 64 * 4096;
  int rem = cnt_e - mt * 128;
#pragma unroll
  for (int ni = 0; ni < 2; ni++) {
    int cc = nt * 64 + wn * 32 + ni * 16 + l15;
    size_t cb = hbase + (size_t)(cc >> 5) * 4096 + (size_t)((cc >> 3) & 3) * 1024 + (cc & 7);
#pragma unroll
    for (int mi = 0; mi < 4; mi++)
#pragma unroll
      for (int r = 0; r < 4; r++) {
        int row = wm * 64 + mi * 16 + quad * 4 + r;
        if (row < rem) {
          float g = accg[mi][ni][r], u = accu[mi][ni][r];
          float sv = g / (1.f + __expf(-g));
          hbuf[cb + (size_t)row * 8] = f2bf(sv * u);
        }
      }
  }
}

// ---------------- GEMM2: out += w * (h * Wd); pure-DMA, atomic scatter ----------------
// BM=128, BN=128, BK=32. grid (16, 8, 9).
__global__ __launch_bounds__(256) void k_gemm2(
    const unsigned short* __restrict__ hbuf, const unsigned short* __restrict__ wdp,
    const int* __restrict__ cnt, const int* __restrict__ poffs,
    const int* __restrict__ tok, const float* __restrict__ wgt,
    float* __restrict__ out) {
  int mt = blockIdx.x, nt = blockIdx.y, e = blockIdx.z;
  int cnt_e = cnt[e];
  if (mt * 128 >= cnt_e) return;
  int po = poffs[e];
  int rt = (po >> 7) + mt;

  __shared__ __align__(16) unsigned short As[4096];   // [q][m][8]
  __shared__ __align__(16) unsigned short BdS[4096];  // [h][q][nn][8]

  int tid = threadIdx.x;
  int lane = tid & 63, w = tid >> 6;
  int quad = lane >> 4, l15 = lane & 15;
  int wm = w >> 1, wn = w & 1;

  const unsigned short* abase = hbuf + (size_t)rt * 64 * 4096;
  const unsigned short* bb0 = wdp + (size_t)e * I_ * H_ + ((size_t)(2 * nt) * 64) * 2048;
  const unsigned short* bb1 = wdp + (size_t)e * I_ * H_ + ((size_t)(2 * nt + 1) * 64) * 2048;

  f32x4 zero = {0.f, 0.f, 0.f, 0.f};
  f32x4 acc[4][4];
#pragma unroll
  for (int mi = 0; mi < 4; mi++)
#pragma unroll
    for (int ni = 0; ni < 4; ni++) acc[mi][ni] = zero;

  for (int kt = 0; kt < 64; kt++) {
    __syncthreads();
    const unsigned short* asrc = abase + (size_t)kt * 4096 + w * 1024 + lane * 8;
    gll16(asrc, &As[w * 1024]);
    gll16(asrc + 512, &As[w * 1024 + 512]);
    gll16(bb0 + (size_t)kt * 2048 + w * 512 + lane * 8, &BdS[w * 512]);
    gll16(bb1 + (size_t)kt * 2048 + w * 512 + lane * 8, &BdS[2048 + w * 512]);
    __syncthreads();
    bf16x8 af[4];
#pragma unroll
    for (int mi = 0; mi < 4; mi++)
      af[mi] = *(const bf16x8*)&As[quad * 1024 + (wm * 64 + mi * 16 + l15) * 8];
#pragma unroll
    for (int ni = 0; ni < 4; ni++) {
      bf16x8 bd = *(const bf16x8*)&BdS[wn * 2048 + quad * 512 + (ni * 16 + l15) * 8];
#pragma unroll
      for (int mi = 0; mi < 4; mi++)
        acc[mi][ni] = __builtin_amdgcn_mfma_f32_16x16x32_bf16(af[mi], bd, acc[mi][ni], 0, 0, 0);
    }
  }
  // epilogue: weighted fp32 atomic scatter
  int rem = cnt_e - mt * 128;
#pragma unroll
  for (int mi = 0; mi < 4; mi++)
#pragma unroll
    for (int r = 0; r < 4; r++) {
      int row = wm * 64 + mi * 16 + quad * 4 + r;
      if (row < rem) {
        int g = po + mt * 128 + row;
        int tt = tok[g];
        float wt = wgt[g];
#pragma unroll
        for (int ni = 0; ni < 4; ni++) {
          int col = nt * 128 + wn * 64 + ni * 16 + l15;
          atomicAdd(&out[(size_t)tt * H_ + col], wt * acc[mi][ni][r]);
        }
      }
    }
}

extern "C" void kernel_launch(void* const* d_in, const int* in_sizes, int n_in,
                              void* d_out, int out_size, void* d_ws, size_t ws_size,
                              hipStream_t stream) {
  const float* x  = (const float*)d_in[0];
  const float* rw = (const float*)d_in[1];
  const float* eg = (const float*)d_in[2];
  const float* eu = (const float*)d_in[3];
  const float* ed = (const float*)d_in[4];
  const float* sg = (const float*)d_in[5];
  const float* su = (const float*)d_in[6];
  const float* sd = (const float*)d_in[7];
  float* out = (float*)d_out;
  char* ws = (char*)d_ws;

  // ws layout (needs ~157.4 MB)
  float* zacc = (float*)(ws + 0);
  float* pacc = (float*)(ws + 16);
  int*   cnt  = (int*)(ws + 64);
  int*   poffs= (int*)(ws + 128);
  int*   cur  = (int*)(ws + 256);
  int*   topi = (int*)(ws + 1024 + 15 * 1024);         // 16K: 2048*2 ints
  float* topw = (float*)(ws + 1024 + 31 * 1024);       // 32K: 2048*2 floats
  int*   tok  = (int*)(ws + 4096 + 60 * 1024);         // tok[7424]
  float* wgt  = (float*)(ws + 4096 + 92 * 1024);       // wgt[7424]
  unsigned short* apack = (unsigned short*)(ws + 131072);                 // 14.68 MB
  unsigned short* hbuf  = (unsigned short*)(ws + 131072 + 14811136);      // 29.36 MB
  unsigned short* wgp   = (unsigned short*)(ws + 131072 + 14811136 + 29491200);
  unsigned short* wup   = (unsigned short*)((char*)wgp + (size_t)NE_ * H_ * I_ * 2);
  unsigned short* wdp   = (unsigned short*)((char*)wup + (size_t)NE_ * H_ * I_ * 2);

  hipMemsetAsync(ws, 0, 4096, stream);
  hipMemsetAsync(out, 0, (size_t)T_ * H_ * 4, stream);

  dim3 gp(64, 32, 3 * NE_);
  k_pack<<<gp, 256, 0, stream>>>(eg, eu, ed, sg, su, sd, wgp, wup, wdp);
  k_router<<<512, 256, 0, stream>>>(x, rw, zacc, pacc, cnt, topi, topw);
  k_scan<<<1, 64, 0, stream>>>(zacc, pacc, cnt, poffs, out + (size_t)T_ * H_);
  k_fill<<<8, 256, 0, stream>>>(topi, topw, poffs, cur, tok, wgt);
  dim3 ga(8, 16, NE_);
  k_packA<<<ga, 256, 0, stream>>>(x, cnt, poffs, tok, apack);
  dim3 g1(16, 32, NE_);
  k_gemm1<<<g1, 256, 0, stream>>>(apack, wgp, wup, cnt, poffs, hbuf);
  dim3 g2(16, 8, NE_);
  k_gemm2<<<g2, 256, 0, stream>>>(hbuf, wdp, cnt, poffs, tok, wgt, out);
}

// Round 5
// 536.555 us; speedup vs baseline: 1.8235x; 1.4519x over previous
//
#include <hip/hip_runtime.h>
#include <hip/hip_bf16.h>
#include <stdint.h>

#define T_ 2048
#define H_ 1024
#define I_ 2048
#define E_ 8
#define NE_ 9            // 8 routed + 1 shared (virtual expert)

typedef __attribute__((ext_vector_type(8))) short bf16x8;
typedef __attribute__((ext_vector_type(4))) float f32x4;

__device__ __forceinline__ unsigned short f2bf(float f) {
  unsigned int u; __builtin_memcpy(&u, &f, 4);
  u = (u + 0x7fffu + ((u >> 16) & 1u)) >> 16;
  return (unsigned short)u;
}
__device__ __forceinline__ void cvt2(float a, float b, unsigned short* dst) {
  __hip_bfloat162 h = __float22bfloat162_rn(float2{a, b});
  __builtin_memcpy(dst, &h, 4);
}
// async global->LDS DMA, 16B per lane; LDS dest = wave-uniform base + lane*16
__device__ __forceinline__ void gll16(const void* g, void* l) {
  __builtin_amdgcn_global_load_lds((const __attribute__((address_space(1))) void*)g,
                                   (__attribute__((address_space(3))) void*)l, 16, 0, 0);
}

// ---------------- pack weights: fp32 [K][N] -> bf16 blocked [nt64][kt32][q][nn][8] ----------------
__global__ __launch_bounds__(256) void k_pack(
    const float* __restrict__ eg, const float* __restrict__ eu, const float* __restrict__ ed,
    const float* __restrict__ sg, const float* __restrict__ su, const float* __restrict__ sd,
    unsigned short* __restrict__ wgp, unsigned short* __restrict__ wup,
    unsigned short* __restrict__ wdp) {
  int kt = blockIdx.x, nt = blockIdx.y, z = blockIdx.z;
  int grp = z / NE_, e = z % NE_;
  int K = (grp == 2) ? I_ : H_;
  int N = (grp == 2) ? H_ : I_;
  if (kt * 32 >= K || nt * 64 >= N) return;
  const float* src; unsigned short* dst;
  if (grp == 0)      { src = (e < E_) ? eg + (size_t)e * H_ * I_ : sg; dst = wgp + (size_t)e * H_ * I_; }
  else if (grp == 1) { src = (e < E_) ? eu + (size_t)e * H_ * I_ : su; dst = wup + (size_t)e * H_ * I_; }
  else               { src = (e < E_) ? ed + (size_t)e * I_ * H_ : sd; dst = wdp + (size_t)e * I_ * H_; }
  int t = threadIdx.x;
  int q = t >> 6, nn = t & 63;
  int k0 = kt * 32 + q * 8, n = nt * 64 + nn;
  unsigned short o[8];
#pragma unroll
  for (int j = 0; j < 8; j += 2) {
    float a = src[(size_t)(k0 + j) * N + n];
    float b = src[(size_t)(k0 + j + 1) * N + n];
    cvt2(a, b, &o[j]);
  }
  size_t tile = ((size_t)nt * (K / 32) + kt) * 2048;
  *(bf16x8*)&dst[tile + q * 512 + nn * 8] = *(bf16x8*)o;
}

// ---------------- router: 1 wave per token; NO global atomics ----------------
__global__ __launch_bounds__(256) void k_router(
    const float* __restrict__ x, const float* __restrict__ rw,
    int* __restrict__ topi, float* __restrict__ topw,
    float* __restrict__ probs, float* __restrict__ lse2) {
  __shared__ float lrw[E_ * H_];  // transposed [e][h], 32 KB
  int tid = threadIdx.x;
#pragma unroll
  for (int i = 0; i < 8; i++) {
    int idx = i * 256 + tid;          // float4 index over 2048
    float4 v = ((const float4*)rw)[idx];
    int f = idx * 4; int h = f >> 3; int e0 = f & 7;   // e0 in {0,4}
    lrw[(e0 + 0) * H_ + h] = v.x;
    lrw[(e0 + 1) * H_ + h] = v.y;
    lrw[(e0 + 2) * H_ + h] = v.z;
    lrw[(e0 + 3) * H_ + h] = v.w;
  }
  __syncthreads();
  int w = tid >> 6, lane = tid & 63;
  int t = blockIdx.x * 4 + w;
  const float* xp = x + (size_t)t * H_ + lane;
  float xr[16];
#pragma unroll
  for (int j = 0; j < 16; j++) xr[j] = xp[j * 64];   // coalesced dword loads
  float acc[E_];
#pragma unroll
  for (int e = 0; e < E_; e++) acc[e] = 0.f;
#pragma unroll
  for (int j = 0; j < 16; j++) {
    float xf = xr[j];
    const float* wp = &lrw[j * 64 + lane];           // lane-stride 1 -> conflict-free
#pragma unroll
    for (int e = 0; e < E_; e++) acc[e] += xf * wp[e * H_];
  }
#pragma unroll
  for (int off = 32; off >= 1; off >>= 1) {
#pragma unroll
    for (int e = 0; e < E_; e++) acc[e] += __shfl_xor(acc[e], off, 64);
  }
  if (lane == 0) {
    float m = acc[0];
#pragma unroll
    for (int e = 1; e < E_; e++) m = fmaxf(m, acc[e]);
    float p[E_], s = 0.f;
#pragma unroll
    for (int e = 0; e < E_; e++) { p[e] = expf(acc[e] - m); s += p[e]; }
    float inv = 1.f / s;
#pragma unroll
    for (int e = 0; e < E_; e++) p[e] *= inv;
    float lse = m + logf(s);
    lse2[t] = lse * lse;
    float4 p0 = {p[0], p[1], p[2], p[3]}, p1 = {p[4], p[5], p[6], p[7]};
    ((float4*)(probs + t * 8))[0] = p0;
    ((float4*)(probs + t * 8))[1] = p1;
    int i0 = 0;
#pragma unroll
    for (int e = 1; e < E_; e++) if (p[e] > p[i0]) i0 = e;
    int i1 = (i0 == 0) ? 1 : 0;
#pragma unroll
    for (int e = 0; e < E_; e++) if (e != i0 && e != i1 && p[e] > p[i1]) i1 = e;
    float w0 = p[i0], w1 = p[i1], wsum = w0 + w1;
    topi[t * 2] = i0; topi[t * 2 + 1] = i1;
    topw[t * 2] = w0 / wsum; topw[t * 2 + 1] = w1 / wsum;
  }
}

// ---------------- reduce: probs/lse2/counts -> cnt, poffs, aux ----------------
__global__ __launch_bounds__(256) void k_reduce(
    const float* __restrict__ probs, const float* __restrict__ lse2,
    const int* __restrict__ topi,
    int* cnt, int* poffs, float* out_aux) {
  __shared__ float sp[256][9];
  __shared__ int sc[256][8];
  int tid = threadIdx.x;
  float ps[9] = {0.f, 0.f, 0.f, 0.f, 0.f, 0.f, 0.f, 0.f, 0.f};
  int c[8] = {0, 0, 0, 0, 0, 0, 0, 0};
  for (int t = tid; t < T_; t += 256) {
#pragma unroll
    for (int e = 0; e < E_; e++) ps[e] += probs[t * 8 + e];
    ps[8] += lse2[t];
    c[topi[t * 2]]++; c[topi[t * 2 + 1]]++;
  }
#pragma unroll
  for (int e = 0; e < 9; e++) sp[tid][e] = ps[e];
#pragma unroll
  for (int e = 0; e < 8; e++) sc[tid][e] = c[e];
  __syncthreads();
  for (int s = 128; s > 0; s >>= 1) {
    if (tid < s) {
#pragma unroll
      for (int e = 0; e < 9; e++) sp[tid][e] += sp[tid + s][e];
#pragma unroll
      for (int e = 0; e < 8; e++) sc[tid][e] += sc[tid + s][e];
    }
    __syncthreads();
  }
  if (tid == 0) {
#pragma unroll
    for (int e = 0; e < E_; e++) cnt[e] = sc[0][e];
    cnt[E_] = T_;
    int po = 0;
    for (int e = 0; e < NE_; e++) { poffs[e] = po; po += ((cnt[e] + 127) >> 7) << 7; }
    poffs[NE_] = po;
    float lb = 0.f;
#pragma unroll
    for (int e = 0; e < E_; e++)
      lb += ((float)cnt[e] / 4096.f) * (sp[0][e] / 2048.f);
    out_aux[0] = 0.01f * 8.f * lb + 0.001f * (sp[0][8] / 2048.f);
  }
}

// ---------------- fill: LDS histogram, 8 global atomics per block ----------------
__global__ __launch_bounds__(256) void k_fill(
    const int* __restrict__ topi, const float* __restrict__ topw,
    const int* __restrict__ poffs, int* cur, int* tok, float* wgt) {
  __shared__ int hist[8];
  __shared__ int base[8];
  int tid = threadIdx.x;
  int t = blockIdx.x * 256 + tid;
  if (tid < 8) hist[tid] = 0;
  __syncthreads();
  int e0 = topi[t * 2], e1 = topi[t * 2 + 1];
  int p0 = atomicAdd(&hist[e0], 1);
  int p1 = atomicAdd(&hist[e1], 1);
  __syncthreads();
  if (tid < 8) base[tid] = atomicAdd(&cur[tid], hist[tid]);
  __syncthreads();
  tok[poffs[e0] + base[e0] + p0] = t; wgt[poffs[e0] + base[e0] + p0] = topw[t * 2];
  tok[poffs[e1] + base[e1] + p1] = t; wgt[poffs[e1] + base[e1] + p1] = topw[t * 2 + 1];
  int p8 = poffs[E_];
  tok[p8 + t] = t;
  wgt[p8 + t] = 1.f;
}

// ---------------- packA: gather x rows -> bf16 blocked A [rt][kt][q][m][8] ----------------
__global__ __launch_bounds__(256) void k_packA(
    const float* __restrict__ x, const int* __restrict__ cnt,
    const int* __restrict__ poffs, const int* __restrict__ tok,
    unsigned short* __restrict__ apack) {
  int kc = blockIdx.x, mt = blockIdx.y, e = blockIdx.z;
  int cnt_e = cnt[e];
  if (mt * 128 >= cnt_e) return;
  int po = poffs[e];
  int rt = (po >> 7) + mt;
  int t = threadIdx.x;
  int m = t & 127, qh = t >> 7;
  int atok = tok[po + min(mt * 128 + m, cnt_e - 1)];
  const float* arow = x + (size_t)atok * H_;
  size_t abase = (size_t)rt * 32 * 4096;
#pragma unroll
  for (int ki = 0; ki < 4; ki++) {
    int kt = kc * 4 + ki;
#pragma unroll
    for (int qo = 0; qo < 2; qo++) {
      int q = qh + qo * 2;
      const float* s = arow + kt * 32 + q * 8;
      float4 v0 = *(const float4*)s, v1 = *(const float4*)(s + 4);
      unsigned short t8[8];
      cvt2(v0.x, v0.y, t8); cvt2(v0.z, v0.w, t8 + 2);
      cvt2(v1.x, v1.y, t8 + 4); cvt2(v1.z, v1.w, t8 + 6);
      *(bf16x8*)&apack[abase + (size_t)kt * 4096 + q * 1024 + m * 8] = *(bf16x8*)t8;
    }
  }
}

// ---------------- GEMM1: h = silu(x*Wg)*(x*Wu); pure-DMA m97-style ----------------
__global__ __launch_bounds__(256) void k_gemm1(
    const unsigned short* __restrict__ apack,
    const unsigned short* __restrict__ wgp, const unsigned short* __restrict__ wup,
    const int* __restrict__ cnt, const int* __restrict__ poffs,
    unsigned short* __restrict__ hbuf) {
  int mt = blockIdx.x, nt = blockIdx.y, e = blockIdx.z;
  int cnt_e = cnt[e];
  if (mt * 128 >= cnt_e) return;
  int po = poffs[e];
  int rt = (po >> 7) + mt;

  __shared__ __align__(16) unsigned short As[4096];   // [q][m][8]
  __shared__ __align__(16) unsigned short BgS[2048];  // [q][nn][8]
  __shared__ __align__(16) unsigned short BuS[2048];

  int tid = threadIdx.x;
  int lane = tid & 63, w = tid >> 6;
  int quad = lane >> 4, l15 = lane & 15;
  int wm = w >> 1, wn = w & 1;

  const unsigned short* abase = apack + (size_t)rt * 32 * 4096;
  const unsigned short* bgb = wgp + (size_t)e * H_ * I_ + (size_t)nt * 32 * 2048;
  const unsigned short* bub = wup + (size_t)e * H_ * I_ + (size_t)nt * 32 * 2048;

  f32x4 zero = {0.f, 0.f, 0.f, 0.f};
  f32x4 accg[4][2], accu[4][2];
#pragma unroll
  for (int mi = 0; mi < 4; mi++)
#pragma unroll
    for (int ni = 0; ni < 2; ni++) { accg[mi][ni] = zero; accu[mi][ni] = zero; }

  for (int kt = 0; kt < 32; kt++) {
    __syncthreads();
    const unsigned short* asrc = abase + (size_t)kt * 4096 + w * 1024 + lane * 8;
    gll16(asrc, &As[w * 1024]);
    gll16(asrc + 512, &As[w * 1024 + 512]);
    gll16(bgb + (size_t)kt * 2048 + w * 512 + lane * 8, &BgS[w * 512]);
    gll16(bub + (size_t)kt * 2048 + w * 512 + lane * 8, &BuS[w * 512]);
    __syncthreads();
    bf16x8 af[4];
#pragma unroll
    for (int mi = 0; mi < 4; mi++)
      af[mi] = *(const bf16x8*)&As[quad * 1024 + (wm * 64 + mi * 16 + l15) * 8];
#pragma unroll
    for (int ni = 0; ni < 2; ni++) {
      bf16x8 bg = *(const bf16x8*)&BgS[quad * 512 + (wn * 32 + ni * 16 + l15) * 8];
      bf16x8 bu = *(const bf16x8*)&BuS[quad * 512 + (wn * 32 + ni * 16 + l15) * 8];
#pragma unroll
      for (int mi = 0; mi < 4; mi++) {
        accg[mi][ni] = __builtin_amdgcn_mfma_f32_16x16x32_bf16(af[mi], bg, accg[mi][ni], 0, 0, 0);
        accu[mi][ni] = __builtin_amdgcn_mfma_f32_16x16x32_bf16(af[mi], bu, accu[mi][ni], 0, 0, 0);
      }
    }
  }
  // epilogue: silu(g)*u -> hbuf in gemm2's packed-A layout [rt][kt2][q2][m][8]
  size_t hbase = (size_t)rt * 64 * 4096;
  int rem = cnt_e - mt * 128;
#pragma unroll
  for (int ni = 0; ni < 2; ni++) {
    int cc = nt * 64 + wn * 32 + ni * 16 + l15;
    size_t cb = hbase + (size_t)(cc >> 5) * 4096 + (size_t)((cc >> 3) & 3) * 1024 + (cc & 7);
#pragma unroll
    for (int mi = 0; mi < 4; mi++)
#pragma unroll
      for (int r = 0; r < 4; r++) {
        int row = wm * 64 + mi * 16 + quad * 4 + r;
        if (row < rem) {
          float g = accg[mi][ni][r], u = accu[mi][ni][r];
          float sv = g / (1.f + __expf(-g));
          hbuf[cb + (size_t)row * 8] = f2bf(sv * u);
        }
      }
  }
}

// ---------------- GEMM2: out += w * (h * Wd); pure-DMA, atomic scatter ----------------
__global__ __launch_bounds__(256) void k_gemm2(
    const unsigned short* __restrict__ hbuf, const unsigned short* __restrict__ wdp,
    const int* __restrict__ cnt, const int* __restrict__ poffs,
    const int* __restrict__ tok, const float* __restrict__ wgt,
    float* __restrict__ out) {
  int mt = blockIdx.x, nt = blockIdx.y, e = blockIdx.z;
  int cnt_e = cnt[e];
  if (mt * 128 >= cnt_e) return;
  int po = poffs[e];
  int rt = (po >> 7) + mt;

  __shared__ __align__(16) unsigned short As[4096];   // [q][m][8]
  __shared__ __align__(16) unsigned short BdS[4096];  // [h][q][nn][8]

  int tid = threadIdx.x;
  int lane = tid & 63, w = tid >> 6;
  int quad = lane >> 4, l15 = lane & 15;
  int wm = w >> 1, wn = w & 1;

  const unsigned short* abase = hbuf + (size_t)rt * 64 * 4096;
  const unsigned short* bb0 = wdp + (size_t)e * I_ * H_ + ((size_t)(2 * nt) * 64) * 2048;
  const unsigned short* bb1 = wdp + (size_t)e * I_ * H_ + ((size_t)(2 * nt + 1) * 64) * 2048;

  f32x4 zero = {0.f, 0.f, 0.f, 0.f};
  f32x4 acc[4][4];
#pragma unroll
  for (int mi = 0; mi < 4; mi++)
#pragma unroll
    for (int ni = 0; ni < 4; ni++) acc[mi][ni] = zero;

  for (int kt = 0; kt < 64; kt++) {
    __syncthreads();
    const unsigned short* asrc = abase + (size_t)kt * 4096 + w * 1024 + lane * 8;
    gll16(asrc, &As[w * 1024]);
    gll16(asrc + 512, &As[w * 1024 + 512]);
    gll16(bb0 + (size_t)kt * 2048 + w * 512 + lane * 8, &BdS[w * 512]);
    gll16(bb1 + (size_t)kt * 2048 + w * 512 + lane * 8, &BdS[2048 + w * 512]);
    __syncthreads();
    bf16x8 af[4];
#pragma unroll
    for (int mi = 0; mi < 4; mi++)
      af[mi] = *(const bf16x8*)&As[quad * 1024 + (wm * 64 + mi * 16 + l15) * 8];
#pragma unroll
    for (int ni = 0; ni < 4; ni++) {
      bf16x8 bd = *(const bf16x8*)&BdS[wn * 2048 + quad * 512 + (ni * 16 + l15) * 8];
#pragma unroll
      for (int mi = 0; mi < 4; mi++)
        acc[mi][ni] = __builtin_amdgcn_mfma_f32_16x16x32_bf16(af[mi], bd, acc[mi][ni], 0, 0, 0);
    }
  }
  // epilogue: weighted fp32 atomic scatter
  int rem = cnt_e - mt * 128;
#pragma unroll
  for (int mi = 0; mi < 4; mi++)
#pragma unroll
    for (int r = 0; r < 4; r++) {
      int row = wm * 64 + mi * 16 + quad * 4 + r;
      if (row < rem) {
        int g = po + mt * 128 + row;
        int tt = tok[g];
        float wt = wgt[g];
#pragma unroll
        for (int ni = 0; ni < 4; ni++) {
          int col = nt * 128 + wn * 64 + ni * 16 + l15;
          atomicAdd(&out[(size_t)tt * H_ + col], wt * acc[mi][ni][r]);
        }
      }
    }
}

extern "C" void kernel_launch(void* const* d_in, const int* in_sizes, int n_in,
                              void* d_out, int out_size, void* d_ws, size_t ws_size,
                              hipStream_t stream) {
  const float* x  = (const float*)d_in[0];
  const float* rw = (const float*)d_in[1];
  const float* eg = (const float*)d_in[2];
  const float* eu = (const float*)d_in[3];
  const float* ed = (const float*)d_in[4];
  const float* sg = (const float*)d_in[5];
  const float* su = (const float*)d_in[6];
  const float* sd = (const float*)d_in[7];
  float* out = (float*)d_out;
  char* ws = (char*)d_ws;

  int*   cnt  = (int*)(ws + 64);
  int*   poffs= (int*)(ws + 128);
  int*   cur  = (int*)(ws + 256);
  int*   topi = (int*)(ws + 4096);
  float* topw = (float*)(ws + 4096 + 16384);
  int*   tok  = (int*)(ws + 36864);
  float* wgt  = (float*)(ws + 66560);
  unsigned short* apack = (unsigned short*)(ws + 131072);                 // 14.68 MB
  unsigned short* hbuf  = (unsigned short*)(ws + 131072 + 14811136);      // 29.36 MB used max
  float* probs = (float*)(ws + 44302336);   // tail slack of hbuf region (64 KB)
  float* lse2  = (float*)(ws + 44367872);   // 8 KB
  unsigned short* wgp   = (unsigned short*)(ws + 131072 + 14811136 + 29491200);
  unsigned short* wup   = (unsigned short*)((char*)wgp + (size_t)NE_ * H_ * I_ * 2);
  unsigned short* wdp   = (unsigned short*)((char*)wup + (size_t)NE_ * H_ * I_ * 2);

  hipMemsetAsync(ws, 0, 4096, stream);
  hipMemsetAsync(out, 0, (size_t)T_ * H_ * 4, stream);

  dim3 gp(64, 32, 3 * NE_);
  k_pack<<<gp, 256, 0, stream>>>(eg, eu, ed, sg, su, sd, wgp, wup, wdp);
  k_router<<<512, 256, 0, stream>>>(x, rw, topi, topw, probs, lse2);
  k_reduce<<<1, 256, 0, stream>>>(probs, lse2, topi, cnt, poffs, out + (size_t)T_ * H_);
  k_fill<<<8, 256, 0, stream>>>(topi, topw, poffs, cur, tok, wgt);
  dim3 ga(8, 16, NE_);
  k_packA<<<ga, 256, 0, stream>>>(x, cnt, poffs, tok, apack);
  dim3 g1(16, 32, NE_);
  k_gemm1<<<g1, 256, 0, stream>>>(apack, wgp, wup, cnt, poffs, hbuf);
  dim3 g2(16, 8, NE_);
  k_gemm2<<<g2, 256, 0, stream>>>(hbuf, wdp, cnt, poffs, tok, wgt, out);
}